// Round 10
// baseline (83.005 us; speedup 1.0000x reference)
//
#include <hip/hip_runtime.h>
#include <math.h>

// Problem constants
#define NB 1024
#define NC 5994
#define NCP 6144   // padded row count for wb (48 c-tiles of 128)
#define NK 512
#define NA 3
#define NT 48      // total K-steps: NA * (NK/32)
#define SCALE_F 30.0f
#define NPT 24     // ceil(NC/256) for row_loss

// Margin constants
#define COS_M_F 0.9800665778412416f
#define SIN_M_F 0.19866933079506122f
#define TH_F (-0.9800665778412416f)
#define MM_F 0.039733866159012244f
#define SUB_COS_M_F 0.9982005399352042f
#define SUB_SIN_M_F (-0.05996400647944459f)
#define SUB_TH_F (-0.9982005399352042f)
#define SUB_MM_F 0.0035978403887666754f

typedef __attribute__((ext_vector_type(8))) short short8;   // 8 bf16 (4 VGPRs)
typedef __attribute__((ext_vector_type(4))) float f32x4;    // MFMA accumulator

__device__ __forceinline__ float waveReduceSum(float v) {
#pragma unroll
  for (int off = 32; off > 0; off >>= 1) v += __shfl_down(v, off);
  return v;
}

__device__ __forceinline__ void waveArgMax(float& v, int& i) {
#pragma unroll
  for (int off = 32; off > 0; off >>= 1) {
    float ov = __shfl_down(v, off);
    int oi = __shfl_down(i, off);
    if (ov > v || (ov == v && (unsigned)oi < (unsigned)i)) { v = ov; i = oi; }
  }
}

__device__ __forceinline__ ushort f2bf(float f) {
  unsigned u = __float_as_uint(f);
  u += 0x7FFFu + ((u >> 16) & 1u);
  return (ushort)(u >> 16);
}

__device__ __forceinline__ void load_lds16(const ushort* g, ushort* l) {
  __builtin_amdgcn_global_load_lds(
      (const __attribute__((address_space(1))) unsigned int*)g,
      (__attribute__((address_space(3))) unsigned int*)l, 16, 0, 0);
}

// Fused L2-normalize + bf16 convert. 4 rows per 256-thread block (1 row/wave).
__global__ __launch_bounds__(256) void norm_convert(const float* __restrict__ x,
                                                    const float* __restrict__ w,
                                                    ushort* __restrict__ xb,
                                                    ushort* __restrict__ wb) {
  const int row = blockIdx.x * 4 + (threadIdx.x >> 6);
  const int lane = threadIdx.x & 63;
  const float* src;
  ushort* dst;
  if (row < NB) {
    src = x + (size_t)row * NK;
    dst = xb + (size_t)row * NK;
  } else {
    const int r = row - NB;           // 0 .. NA*NCP-1
    const int a = r / NCP, c = r % NCP;
    dst = wb + (size_t)r * NK;
    if (c >= NC) {                    // zero-fill padding row
      ushort4 z = {0, 0, 0, 0};
      *(ushort4*)(dst + lane * 4) = z;
      *(ushort4*)(dst + 256 + lane * 4) = z;
      return;
    }
    src = w + ((size_t)a * NC + c) * NK;
  }
  const float4 v0 = *(const float4*)(src + lane * 4);
  const float4 v1 = *(const float4*)(src + 256 + lane * 4);
  float ss = v0.x * v0.x + v0.y * v0.y + v0.z * v0.z + v0.w * v0.w +
             v1.x * v1.x + v1.y * v1.y + v1.z * v1.z + v1.w * v1.w;
  ss = waveReduceSum(ss);
  ss = __shfl(ss, 0);
  const float rn = 1.0f / fmaxf(sqrtf(ss), 1e-12f);
  ushort4 o0 = {f2bf(v0.x * rn), f2bf(v0.y * rn), f2bf(v0.z * rn), f2bf(v0.w * rn)};
  ushort4 o1 = {f2bf(v1.x * rn), f2bf(v1.y * rn), f2bf(v1.z * rn), f2bf(v1.w * rn)};
  *(ushort4*)(dst + lane * 4) = o0;
  *(ushort4*)(dst + 256 + lane * 4) = o1;
}

// cosine[b,c] = max_a dot(xn[b,:], wn[a,c,:])  via bf16 MFMA, fp32 accum.
// R8 structure (64x128 tile, 2 waves, slot-rotation swizzle, XCD swizzle,
// grid 768 = 3 blocks/CU) + COUNTED-vmcnt pipeline (T4, m218 mechanism):
// 4 LDS buffers, lookahead-2 prefetch; per step:
//   stage(t+2) -> s_waitcnt vmcnt(12) [stages t+1,t+2 stay IN FLIGHT]
//   -> raw s_barrier (no compiler vmcnt(0) drain!) -> ds_read -> 16 MFMA.
// Race audit: buffer read at step t is next written by a stage issued at
// step t+2 — two barriers later; a wave's ds_reads complete (lgkmcnt before
// MFMA) before it passes barrier t+1 => no WAR. Cross-wave availability:
// every wave passes barrier t only after its own vmcnt wait => stage(t)
// fully landed. Barriers kept => no R6/R9-style race/crash.
__global__ __launch_bounds__(128) void cos_gemm_mfma(const ushort* __restrict__ Xb,
                                                     const ushort* __restrict__ Wb,
                                                     float* __restrict__ cosine) {
  __shared__ ushort sA0[2048], sA1[2048], sA2[2048], sA3[2048];  // 4 KB each
  __shared__ ushort sB0[4096], sB1[4096], sB2[4096], sB3[4096];  // 8 KB each
  const int tid = threadIdx.x;
  const int lane = tid & 63;
  const int w = tid >> 6;           // 0..1

  // swizzle: id = (cx&7) + 8*by + 128*(cx>>3)  (bijective on 8*16*6 = 768)
  const int id = blockIdx.x;
  const int cx = (id & 7) + ((id >> 7) << 3);   // 0..47
  const int by = (id >> 3) & 15;                // 0..15
  const int b0 = by * 64;
  const int c0 = cx * 128;

  // staging source: quad-contiguous rows, chunk rotated (R8-proven):
  const int lrow = lane >> 2;
  const int skg = ((lane & 3) - ((lane >> 3) & 3)) & 3;
  const ushort* gA = Xb + (size_t)(b0 + w * 32 + lrow) * NK + skg * 8;
  const ushort* gB = Wb + (size_t)(c0 + w * 64 + lrow) * NK + skg * 8;
  const int ldsA = w * 1024;        // A sub-blocks {2w,2w+1}
  const int ldsB = w * 2048;        // B sub-blocks {4w..4w+3}
  const int w4 = w * 4;

  // fragment-read offset: r*32 + (((kg + (r>>1)) & 3) * 8)  (R8-proven)
  const int r = lane & 15;
  const int kg = lane >> 4;
  const int rdoff = r * 32 + (((kg + (r >> 1)) & 3) * 8);

  f32x4 best[4][4];
  f32x4 acc[4][4];
#pragma unroll
  for (int i = 0; i < 4; ++i)
#pragma unroll
    for (int j = 0; j < 4; ++j) {
#pragma unroll
      for (int q = 0; q < 4; ++q) best[i][j][q] = -INFINITY;
      acc[i][j] = (f32x4)(0.f);
    }

#define STAGE(TT, SAw, SBw)                                                     \
  {                                                                             \
    const int tt_ = (TT);                                                       \
    const int k0 = (tt_ & 15) << 5;                                             \
    const size_t boff = (size_t)(tt_ >> 4) * NCP * NK + k0;                     \
    load_lds16(gA + k0, (ushort*)SAw + ldsA);                                   \
    load_lds16(gA + k0 + 16 * NK, (ushort*)SAw + ldsA + 512);                   \
    _Pragma("unroll") for (int j = 0; j < 4; ++j)                               \
        load_lds16(gB + boff + (size_t)j * 16 * NK, (ushort*)SBw + ldsB + j * 512); \
  }

  // prologue: 2-deep prefetch into buffers 0,1
  STAGE(0, sA0, sB0)
  STAGE(1, sA1, sB1)

#define GEMM_BODY(T, SAr, SBr, SAw, SBw)                                        \
  {                                                                             \
    const int t_ = (T);                                                         \
    if (t_ + 2 < NT) STAGE(t_ + 2, SAw, SBw)                                    \
    if (t_ + 2 < NT) {                                                          \
      asm volatile("s_waitcnt vmcnt(12)" ::: "memory");  /* stage(t) landed */  \
    } else if (t_ + 1 < NT) {                                                   \
      asm volatile("s_waitcnt vmcnt(6)" ::: "memory");                          \
    } else {                                                                    \
      asm volatile("s_waitcnt vmcnt(0)" ::: "memory");                          \
    }                                                                           \
    __builtin_amdgcn_sched_barrier(0);                                          \
    __builtin_amdgcn_s_barrier();                                               \
    __builtin_amdgcn_sched_barrier(0);                                          \
    short8 af[4], bf[4];                                                        \
    _Pragma("unroll") for (int mi = 0; mi < 4; ++mi)                            \
        af[mi] = *(const short8*)&SAr[mi * 512 + rdoff];                        \
    _Pragma("unroll") for (int ni = 0; ni < 4; ++ni)                            \
        bf[ni] = *(const short8*)&SBr[(w4 + ni) * 512 + rdoff];                 \
    _Pragma("unroll") for (int mi = 0; mi < 4; ++mi)                            \
        _Pragma("unroll") for (int ni = 0; ni < 4; ++ni)                        \
            acc[mi][ni] = __builtin_amdgcn_mfma_f32_16x16x32_bf16(              \
                af[mi], bf[ni], acc[mi][ni], 0, 0, 0);                          \
    if ((t_ & 15) == 15) {                                                      \
      _Pragma("unroll") for (int i = 0; i < 4; ++i)                             \
          _Pragma("unroll") for (int j = 0; j < 4; ++j) {                       \
        _Pragma("unroll") for (int q = 0; q < 4; ++q)                           \
            best[i][j][q] = fmaxf(best[i][j][q], acc[i][j][q]);                 \
        acc[i][j] = (f32x4)(0.f);                                               \
      }                                                                         \
    }                                                                           \
  }

  for (int t = 0; t < NT; t += 4) {
    GEMM_BODY(t,     sA0, sB0, sA2, sB2)
    GEMM_BODY(t + 1, sA1, sB1, sA3, sB3)
    GEMM_BODY(t + 2, sA2, sB2, sA0, sB0)
    GEMM_BODY(t + 3, sA3, sB3, sA1, sB1)
  }
#undef GEMM_BODY
#undef STAGE

  // C/D layout: col = lane&15, row = (lane>>4)*4 + q   [measured m89/m91]
  const int q4 = (lane >> 4) * 4;
#pragma unroll
  for (int ni = 0; ni < 4; ++ni) {
    const int col = c0 + w * 64 + ni * 16 + r;
    if (col < NC) {
#pragma unroll
      for (int mi = 0; mi < 4; ++mi) {
        const int row0 = b0 + mi * 16 + q4;
#pragma unroll
        for (int q = 0; q < 4; ++q)
          cosine[(size_t)(row0 + q) * NC + col] = best[mi][ni][q];
      }
    }
  }
}

// Per-row loss (R5/R8-proven): 256 threads/row, register-resident 24/thread.
__global__ __launch_bounds__(256) void row_loss(const float* __restrict__ cosine,
                                                const int* __restrict__ label,
                                                float* __restrict__ loss_b,
                                                float* __restrict__ corr_b) {
  __shared__ float swv[4];
  __shared__ int swi[4];
  __shared__ float s_red[4];
  __shared__ float s_maxv;
  __shared__ float s_cosL;
  __shared__ float topv[6];
  __shared__ int topi[6];

  const int b = blockIdx.x, tid = threadIdx.x;
  const int wv = tid >> 6;
  const int lab = label[b];
  const float* row = cosine + (size_t)b * NC;

  float v[NPT];
  float bv = -INFINITY;
  int bi = -1;
#pragma unroll
  for (int j = 0; j < NPT; ++j) {
    const int i = tid + j * 256;
    v[j] = (i < NC) ? row[i] : -INFINITY;
    if (v[j] > bv) { bv = v[j]; bi = i; }
  }
  if (tid == (lab & 255)) s_cosL = v[lab >> 8];
  waveArgMax(bv, bi);
  if ((tid & 63) == 0) { swv[wv] = bv; swi[wv] = bi; }
  __syncthreads();
  if (tid == 0) {
    float mv = swv[0]; int mi = swi[0];
    for (int q = 1; q < 4; ++q)
      if (swv[q] > mv || (swv[q] == mv && (unsigned)swi[q] < (unsigned)mi)) { mv = swv[q]; mi = swi[q]; }
    s_maxv = mv; topv[0] = mv; topi[0] = mi;
  }
  __syncthreads();
  const float maxv = s_maxv;

  float ps = 0.f;
#pragma unroll
  for (int j = 0; j < NPT; ++j) ps += __expf(SCALE_F * (v[j] - maxv));
  ps = waveReduceSum(ps);
  if ((tid & 63) == 0) s_red[wv] = ps;

  unsigned excl = 0;
  {
    const int wi = topi[0];
    if ((wi & 255) == tid) excl |= 1u << (wi >> 8);
  }

  for (int e = 1; e < 6; ++e) {
    float lv = -INFINITY;
    int li = -1;
#pragma unroll
    for (int j = 0; j < NPT; ++j)
      if (!((excl >> j) & 1u) && v[j] > lv) { lv = v[j]; li = tid + j * 256; }
    waveArgMax(lv, li);
    if ((tid & 63) == 0) { swv[wv] = lv; swi[wv] = li; }
    __syncthreads();
    if (tid == 0) {
      float mv = swv[0]; int mi = swi[0];
      for (int q = 1; q < 4; ++q)
        if (swv[q] > mv || (swv[q] == mv && (unsigned)swi[q] < (unsigned)mi)) { mv = swv[q]; mi = swi[q]; }
      topv[e] = mv; topi[e] = mi;
    }
    __syncthreads();
    const int wi = topi[e];
    if ((wi & 255) == tid) excl |= 1u << (wi >> 8);
  }

  if (tid == 0) {
    const float S = s_red[0] + s_red[1] + s_red[2] + s_red[3];
    const float m = SCALE_F * maxv;
    const float cosL = s_cosL;
    const float sineL = sqrtf(fminf(fmaxf(1.f - cosL * cosL, 0.f), 1.f));
    const float phiL = (cosL - TH_F > 0.f) ? (cosL * COS_M_F - sineL * SIN_M_F) : (cosL - MM_F);
    float adj = __expf(SCALE_F * phiL - m) - __expf(SCALE_F * cosL - m);
    int cnt = 0;
    for (int e = 0; e < 6 && cnt < 5; ++e) {
      if (topi[e] == lab) continue;
      const float c = topv[e];
      const float sine = sqrtf(fminf(fmaxf(1.f - c * c, 0.f), 1.f));
      const float sp = (c - SUB_TH_F > 0.f) ? (c * SUB_COS_M_F - sine * SUB_SIN_M_F) : (c - SUB_MM_F);
      adj += __expf(SCALE_F * sp - m) - __expf(SCALE_F * c - m);
      ++cnt;
    }
    const float Sp = S + adj;
    loss_b[b] = (logf(Sp) + m) - SCALE_F * phiL;
    corr_b[b] = (topi[0] == lab) ? 1.f : 0.f;
  }
}

__global__ __launch_bounds__(256) void finalize(const float* __restrict__ loss_b,
                                                const float* __restrict__ corr_b,
                                                float* __restrict__ out) {
  const int tid = threadIdx.x;
  float ls = 0.f, cs = 0.f;
  for (int i = tid; i < NB; i += 256) { ls += loss_b[i]; cs += corr_b[i]; }
  ls = waveReduceSum(ls);
  cs = waveReduceSum(cs);
  __shared__ float sl[4], sc[4];
  if ((tid & 63) == 0) { sl[tid >> 6] = ls; sc[tid >> 6] = cs; }
  __syncthreads();
  if (tid == 0) {
    const float L = sl[0] + sl[1] + sl[2] + sl[3];
    const float Cr = sc[0] + sc[1] + sc[2] + sc[3];
    out[0] = L / (float)NB;
    out[1] = Cr / (float)NB * 100.f;
  }
}

extern "C" void kernel_launch(void* const* d_in, const int* in_sizes, int n_in,
                              void* d_out, int out_size, void* d_ws, size_t ws_size,
                              hipStream_t stream) {
  const float* x = (const float*)d_in[0];      // [1024, 512]
  const float* w = (const float*)d_in[1];      // [3, 5994, 512]
  const int* label = (const int*)d_in[2];      // [1024]
  float* out = (float*)d_out;                  // [2] = {loss, prec1}
  char* ws = (char*)d_ws;

  // workspace layout (bytes) — identical footprint to R5/R8 (proven):
  ushort* xb = (ushort*)ws;                                    // 1,048,576
  ushort* wb = (ushort*)(ws + 1048576);                        // 18,874,368
  float* cosine = (float*)(ws + 1048576 + 18874368);           // 24,551,424 (packed, stride 5994)
  float* loss_b = (float*)ws;                                  // reuses dead xb
  float* corr_b = (float*)(ws + 4096);

  norm_convert<<<(NB + NA * NCP) / 4, 256, 0, stream>>>(x, w, xb, wb);
  cos_gemm_mfma<<<16 * 48, 128, 0, stream>>>(xb, wb, cosine);
  row_loss<<<NB, 256, 0, stream>>>(cosine, label, loss_b, corr_b);
  finalize<<<1, 256, 0, stream>>>(loss_b, corr_b, out);
}

// Round 11
// 82.284 us; speedup vs baseline: 1.0088x; 1.0088x over previous
//
#include <hip/hip_runtime.h>
#include <math.h>

// Problem constants
#define NB 1024
#define NC 5994
#define NCP 6144   // padded row count for wb (48 c-tiles of 128)
#define NK 512
#define NA 3
#define NT 48      // total K-steps: NA * (NK/32)
#define SCALE_F 30.0f
#define NPT 24     // ceil(NC/256) for row_loss

// Margin constants
#define COS_M_F 0.9800665778412416f
#define SIN_M_F 0.19866933079506122f
#define TH_F (-0.9800665778412416f)
#define MM_F 0.039733866159012244f
#define SUB_COS_M_F 0.9982005399352042f
#define SUB_SIN_M_F (-0.05996400647944459f)
#define SUB_TH_F (-0.9982005399352042f)
#define SUB_MM_F 0.0035978403887666754f

typedef __attribute__((ext_vector_type(8))) short short8;   // 8 bf16 (4 VGPRs)
typedef __attribute__((ext_vector_type(4))) float f32x4;    // MFMA accumulator

__device__ __forceinline__ float waveReduceSum(float v) {
#pragma unroll
  for (int off = 32; off > 0; off >>= 1) v += __shfl_down(v, off);
  return v;
}

__device__ __forceinline__ void waveArgMax(float& v, int& i) {
#pragma unroll
  for (int off = 32; off > 0; off >>= 1) {
    float ov = __shfl_down(v, off);
    int oi = __shfl_down(i, off);
    if (ov > v || (ov == v && (unsigned)oi < (unsigned)i)) { v = ov; i = oi; }
  }
}

__device__ __forceinline__ ushort f2bf(float f) {
  unsigned u = __float_as_uint(f);
  u += 0x7FFFu + ((u >> 16) & 1u);
  return (ushort)(u >> 16);
}

__device__ __forceinline__ void load_lds16(const ushort* g, ushort* l) {
  __builtin_amdgcn_global_load_lds(
      (const __attribute__((address_space(1))) unsigned int*)g,
      (__attribute__((address_space(3))) unsigned int*)l, 16, 0, 0);
}

// Fused L2-normalize + bf16 convert. 4 rows per 256-thread block (1 row/wave).
__global__ __launch_bounds__(256) void norm_convert(const float* __restrict__ x,
                                                    const float* __restrict__ w,
                                                    ushort* __restrict__ xb,
                                                    ushort* __restrict__ wb) {
  const int row = blockIdx.x * 4 + (threadIdx.x >> 6);
  const int lane = threadIdx.x & 63;
  const float* src;
  ushort* dst;
  if (row < NB) {
    src = x + (size_t)row * NK;
    dst = xb + (size_t)row * NK;
  } else {
    const int r = row - NB;           // 0 .. NA*NCP-1
    const int a = r / NCP, c = r % NCP;
    dst = wb + (size_t)r * NK;
    if (c >= NC) {                    // zero-fill padding row
      ushort4 z = {0, 0, 0, 0};
      *(ushort4*)(dst + lane * 4) = z;
      *(ushort4*)(dst + 256 + lane * 4) = z;
      return;
    }
    src = w + ((size_t)a * NC + c) * NK;
  }
  const float4 v0 = *(const float4*)(src + lane * 4);
  const float4 v1 = *(const float4*)(src + 256 + lane * 4);
  float ss = v0.x * v0.x + v0.y * v0.y + v0.z * v0.z + v0.w * v0.w +
             v1.x * v1.x + v1.y * v1.y + v1.z * v1.z + v1.w * v1.w;
  ss = waveReduceSum(ss);
  ss = __shfl(ss, 0);
  const float rn = 1.0f / fmaxf(sqrtf(ss), 1e-12f);
  ushort4 o0 = {f2bf(v0.x * rn), f2bf(v0.y * rn), f2bf(v0.z * rn), f2bf(v0.w * rn)};
  ushort4 o1 = {f2bf(v1.x * rn), f2bf(v1.y * rn), f2bf(v1.z * rn), f2bf(v1.w * rn)};
  *(ushort4*)(dst + lane * 4) = o0;
  *(ushort4*)(dst + 256 + lane * 4) = o1;
}

// cosine[b,c] = max_a dot(xn[b,:], wn[a,c,:])  via bf16 MFMA, fp32 accum.
// R8-proven core (2 waves, double-buffer, ONE __syncthreads per K-step,
// slot-rotation swizzle: VMEM quad-coalesced + conflict-free ds_read),
// tile shrunk to 32x128 -> grid 32x48 = 1536 blocks = 6 blocks/CU =
// 12 waves/CU = 3 waves/SIMD (2x R8's TLP; we are latency-bound with all
// pipes idle, so wave-level overlap is the binding resource — m114).
// LDS 20KB/block (grid-capped at 6 blocks/CU, not LDS-capped).
// XCD swizzle: id = (cx&7) + 8*by + 256*(cx>>3), bijective on 8*32*6=1536;
// all 32 sharers of a B-panel land on one XCD L2 (proven FETCH 84->15MB).
__global__ __launch_bounds__(128) void cos_gemm_mfma(const ushort* __restrict__ Xb,
                                                     const ushort* __restrict__ Wb,
                                                     float* __restrict__ cosine) {
  __shared__ ushort sA0[32 * 32];   // 2 KB each (2 sub-blocks)
  __shared__ ushort sA1[32 * 32];
  __shared__ ushort sB0[128 * 32];  // 8 KB each (8 sub-blocks)
  __shared__ ushort sB1[128 * 32];
  const int tid = threadIdx.x;
  const int lane = tid & 63;
  const int w = tid >> 6;           // 0..1

  const int id = blockIdx.x;
  const int cx = (id & 7) + ((id >> 8) << 3);   // 0..47
  const int by = (id >> 3) & 31;                // 0..31
  const int b0 = by * 32;
  const int c0 = cx * 128;

  // staging source: quad-contiguous rows, chunk rotated (R8-proven):
  const int lrow = lane >> 2;
  const int skg = ((lane & 3) - ((lane >> 3) & 3)) & 3;
  // wave w stages A sub-block w (rows 16w..16w+15) and B sub-blocks 4w..4w+3
  const ushort* gA = Xb + (size_t)(b0 + w * 16 + lrow) * NK + skg * 8;
  const ushort* gB = Wb + (size_t)(c0 + w * 64 + lrow) * NK + skg * 8;
  const int ldsA = w * 512;         // A sub-block w
  const int ldsB = w * 2048;        // B sub-blocks {4w..4w+3}
  const int w4 = w * 4;

  // fragment-read offset: r*32 + (((kg + (r>>1)) & 3) * 8)  (R8-proven)
  const int r = lane & 15;
  const int kg = lane >> 4;
  const int rdoff = r * 32 + (((kg + (r >> 1)) & 3) * 8);

  f32x4 best[2][4];
  f32x4 acc[2][4];
#pragma unroll
  for (int i = 0; i < 2; ++i)
#pragma unroll
    for (int j = 0; j < 4; ++j) {
#pragma unroll
      for (int q = 0; q < 4; ++q) best[i][j][q] = -INFINITY;
      acc[i][j] = (f32x4)(0.f);
    }

  // prologue: stage t=0 into buffer 0  (1 A load + 4 B loads per wave)
  load_lds16(gA, (ushort*)sA0 + ldsA);
#pragma unroll
  for (int j = 0; j < 4; ++j)
    load_lds16(gB + (size_t)j * 16 * NK, (ushort*)sB0 + ldsB + j * 512);
  __syncthreads();

#define GEMM_BODY(T, SAr, SBr, SAw, SBw)                                        \
  {                                                                             \
    const int t_ = (T);                                                         \
    if (t_ + 1 < NT) {                                                          \
      const int tn = t_ + 1;                                                    \
      const int k0 = (tn & 15) << 5;                                            \
      const size_t boff = (size_t)(tn >> 4) * NCP * NK + k0;                    \
      load_lds16(gA + k0, (ushort*)SAw + ldsA);                                 \
      _Pragma("unroll") for (int j = 0; j < 4; ++j)                             \
          load_lds16(gB + boff + (size_t)j * 16 * NK,                           \
                     (ushort*)SBw + ldsB + j * 512);                            \
    }                                                                           \
    short8 af[2], bf[4];                                                        \
    _Pragma("unroll") for (int mi = 0; mi < 2; ++mi)                            \
        af[mi] = *(const short8*)&SAr[mi * 512 + rdoff];                        \
    _Pragma("unroll") for (int ni = 0; ni < 4; ++ni)                            \
        bf[ni] = *(const short8*)&SBr[(w4 + ni) * 512 + rdoff];                 \
    _Pragma("unroll") for (int mi = 0; mi < 2; ++mi)                            \
        _Pragma("unroll") for (int ni = 0; ni < 4; ++ni)                        \
            acc[mi][ni] = __builtin_amdgcn_mfma_f32_16x16x32_bf16(              \
                af[mi], bf[ni], acc[mi][ni], 0, 0, 0);                          \
    if ((t_ & 15) == 15) {                                                      \
      _Pragma("unroll") for (int i = 0; i < 2; ++i)                             \
          _Pragma("unroll") for (int j = 0; j < 4; ++j) {                       \
        _Pragma("unroll") for (int q = 0; q < 4; ++q)                           \
            best[i][j][q] = fmaxf(best[i][j][q], acc[i][j][q]);                 \
        acc[i][j] = (f32x4)(0.f);                                               \
      }                                                                         \
    }                                                                           \
    __syncthreads();                                                            \
  }

  for (int t = 0; t < NT; t += 2) {
    GEMM_BODY(t, sA0, sB0, sA1, sB1)
    GEMM_BODY(t + 1, sA1, sB1, sA0, sB0)
  }
#undef GEMM_BODY

  // C/D layout: col = lane&15, row = (lane>>4)*4 + q   [measured m89/m91]
  const int q4 = (lane >> 4) * 4;
#pragma unroll
  for (int ni = 0; ni < 4; ++ni) {
    const int col = c0 + w * 64 + ni * 16 + r;
    if (col < NC) {
#pragma unroll
      for (int mi = 0; mi < 2; ++mi) {
        const int row0 = b0 + mi * 16 + q4;
#pragma unroll
        for (int q = 0; q < 4; ++q)
          cosine[(size_t)(row0 + q) * NC + col] = best[mi][ni][q];
      }
    }
  }
}

// Per-row loss (R5/R8-proven): 256 threads/row, register-resident 24/thread.
__global__ __launch_bounds__(256) void row_loss(const float* __restrict__ cosine,
                                                const int* __restrict__ label,
                                                float* __restrict__ loss_b,
                                                float* __restrict__ corr_b) {
  __shared__ float swv[4];
  __shared__ int swi[4];
  __shared__ float s_red[4];
  __shared__ float s_maxv;
  __shared__ float s_cosL;
  __shared__ float topv[6];
  __shared__ int topi[6];

  const int b = blockIdx.x, tid = threadIdx.x;
  const int wv = tid >> 6;
  const int lab = label[b];
  const float* row = cosine + (size_t)b * NC;

  float v[NPT];
  float bv = -INFINITY;
  int bi = -1;
#pragma unroll
  for (int j = 0; j < NPT; ++j) {
    const int i = tid + j * 256;
    v[j] = (i < NC) ? row[i] : -INFINITY;
    if (v[j] > bv) { bv = v[j]; bi = i; }
  }
  if (tid == (lab & 255)) s_cosL = v[lab >> 8];
  waveArgMax(bv, bi);
  if ((tid & 63) == 0) { swv[wv] = bv; swi[wv] = bi; }
  __syncthreads();
  if (tid == 0) {
    float mv = swv[0]; int mi = swi[0];
    for (int q = 1; q < 4; ++q)
      if (swv[q] > mv || (swv[q] == mv && (unsigned)swi[q] < (unsigned)mi)) { mv = swv[q]; mi = swi[q]; }
    s_maxv = mv; topv[0] = mv; topi[0] = mi;
  }
  __syncthreads();
  const float maxv = s_maxv;

  float ps = 0.f;
#pragma unroll
  for (int j = 0; j < NPT; ++j) ps += __expf(SCALE_F * (v[j] - maxv));
  ps = waveReduceSum(ps);
  if ((tid & 63) == 0) s_red[wv] = ps;

  unsigned excl = 0;
  {
    const int wi = topi[0];
    if ((wi & 255) == tid) excl |= 1u << (wi >> 8);
  }

  for (int e = 1; e < 6; ++e) {
    float lv = -INFINITY;
    int li = -1;
#pragma unroll
    for (int j = 0; j < NPT; ++j)
      if (!((excl >> j) & 1u) && v[j] > lv) { lv = v[j]; li = tid + j * 256; }
    waveArgMax(lv, li);
    if ((tid & 63) == 0) { swv[wv] = lv; swi[wv] = li; }
    __syncthreads();
    if (tid == 0) {
      float mv = swv[0]; int mi = swi[0];
      for (int q = 1; q < 4; ++q)
        if (swv[q] > mv || (swv[q] == mv && (unsigned)swi[q] < (unsigned)mi)) { mv = swv[q]; mi = swi[q]; }
      topv[e] = mv; topi[e] = mi;
    }
    __syncthreads();
    const int wi = topi[e];
    if ((wi & 255) == tid) excl |= 1u << (wi >> 8);
  }

  if (tid == 0) {
    const float S = s_red[0] + s_red[1] + s_red[2] + s_red[3];
    const float m = SCALE_F * maxv;
    const float cosL = s_cosL;
    const float sineL = sqrtf(fminf(fmaxf(1.f - cosL * cosL, 0.f), 1.f));
    const float phiL = (cosL - TH_F > 0.f) ? (cosL * COS_M_F - sineL * SIN_M_F) : (cosL - MM_F);
    float adj = __expf(SCALE_F * phiL - m) - __expf(SCALE_F * cosL - m);
    int cnt = 0;
    for (int e = 0; e < 6 && cnt < 5; ++e) {
      if (topi[e] == lab) continue;
      const float c = topv[e];
      const float sine = sqrtf(fminf(fmaxf(1.f - c * c, 0.f), 1.f));
      const float sp = (c - SUB_TH_F > 0.f) ? (c * SUB_COS_M_F - sine * SUB_SIN_M_F) : (c - SUB_MM_F);
      adj += __expf(SCALE_F * sp - m) - __expf(SCALE_F * c - m);
      ++cnt;
    }
    const float Sp = S + adj;
    loss_b[b] = (logf(Sp) + m) - SCALE_F * phiL;
    corr_b[b] = (topi[0] == lab) ? 1.f : 0.f;
  }
}

__global__ __launch_bounds__(256) void finalize(const float* __restrict__ loss_b,
                                                const float* __restrict__ corr_b,
                                                float* __restrict__ out) {
  const int tid = threadIdx.x;
  float ls = 0.f, cs = 0.f;
  for (int i = tid; i < NB; i += 256) { ls += loss_b[i]; cs += corr_b[i]; }
  ls = waveReduceSum(ls);
  cs = waveReduceSum(cs);
  __shared__ float sl[4], sc[4];
  if ((tid & 63) == 0) { sl[tid >> 6] = ls; sc[tid >> 6] = cs; }
  __syncthreads();
  if (tid == 0) {
    const float L = sl[0] + sl[1] + sl[2] + sl[3];
    const float Cr = sc[0] + sc[1] + sc[2] + sc[3];
    out[0] = L / (float)NB;
    out[1] = Cr / (float)NB * 100.f;
  }
}

extern "C" void kernel_launch(void* const* d_in, const int* in_sizes, int n_in,
                              void* d_out, int out_size, void* d_ws, size_t ws_size,
                              hipStream_t stream) {
  const float* x = (const float*)d_in[0];      // [1024, 512]
  const float* w = (const float*)d_in[1];      // [3, 5994, 512]
  const int* label = (const int*)d_in[2];      // [1024]
  float* out = (float*)d_out;                  // [2] = {loss, prec1}
  char* ws = (char*)d_ws;

  // workspace layout (bytes) — identical footprint to R5/R8 (proven):
  ushort* xb = (ushort*)ws;                                    // 1,048,576
  ushort* wb = (ushort*)(ws + 1048576);                        // 18,874,368
  float* cosine = (float*)(ws + 1048576 + 18874368);           // 24,551,424 (packed, stride 5994)
  float* loss_b = (float*)ws;                                  // reuses dead xb
  float* corr_b = (float*)(ws + 4096);

  norm_convert<<<(NB + NA * NCP) / 4, 256, 0, stream>>>(x, w, xb, wb);
  cos_gemm_mfma<<<32 * 48, 128, 0, stream>>>(xb, wb, cosine);
  row_loss<<<NB, 256, 0, stream>>>(cosine, label, loss_b, corr_b);
  finalize<<<1, 256, 0, stream>>>(loss_b, corr_b, out);
}

// Round 12
// 77.049 us; speedup vs baseline: 1.0773x; 1.0679x over previous
//
#include <hip/hip_runtime.h>
#include <math.h>

// Problem constants
#define NB 1024
#define NC 5994
#define NCP 6144   // padded row count for wb (48 c-tiles of 128)
#define NK 512
#define NA 3
#define NT2 24     // K-steps at BK=64: NA * (NK/64)
#define SCALE_F 30.0f
#define NPT 24     // ceil(NC/256) for row_loss

// Margin constants
#define COS_M_F 0.9800665778412416f
#define SIN_M_F 0.19866933079506122f
#define TH_F (-0.9800665778412416f)
#define MM_F 0.039733866159012244f
#define SUB_COS_M_F 0.9982005399352042f
#define SUB_SIN_M_F (-0.05996400647944459f)
#define SUB_TH_F (-0.9982005399352042f)
#define SUB_MM_F 0.0035978403887666754f

typedef __attribute__((ext_vector_type(8))) short short8;   // 8 bf16 (4 VGPRs)
typedef __attribute__((ext_vector_type(4))) float f32x4;    // MFMA accumulator

__device__ __forceinline__ float waveReduceSum(float v) {
#pragma unroll
  for (int off = 32; off > 0; off >>= 1) v += __shfl_down(v, off);
  return v;
}

__device__ __forceinline__ void waveArgMax(float& v, int& i) {
#pragma unroll
  for (int off = 32; off > 0; off >>= 1) {
    float ov = __shfl_down(v, off);
    int oi = __shfl_down(i, off);
    if (ov > v || (ov == v && (unsigned)oi < (unsigned)i)) { v = ov; i = oi; }
  }
}

__device__ __forceinline__ ushort f2bf(float f) {
  unsigned u = __float_as_uint(f);
  u += 0x7FFFu + ((u >> 16) & 1u);
  return (ushort)(u >> 16);
}

__device__ __forceinline__ void load_lds16(const ushort* g, ushort* l) {
  __builtin_amdgcn_global_load_lds(
      (const __attribute__((address_space(1))) unsigned int*)g,
      (__attribute__((address_space(3))) unsigned int*)l, 16, 0, 0);
}

// Fused L2-normalize + bf16 convert. 4 rows per 256-thread block (1 row/wave).
__global__ __launch_bounds__(256) void norm_convert(const float* __restrict__ x,
                                                    const float* __restrict__ w,
                                                    ushort* __restrict__ xb,
                                                    ushort* __restrict__ wb) {
  const int row = blockIdx.x * 4 + (threadIdx.x >> 6);
  const int lane = threadIdx.x & 63;
  const float* src;
  ushort* dst;
  if (row < NB) {
    src = x + (size_t)row * NK;
    dst = xb + (size_t)row * NK;
  } else {
    const int r = row - NB;           // 0 .. NA*NCP-1
    const int a = r / NCP, c = r % NCP;
    dst = wb + (size_t)r * NK;
    if (c >= NC) {                    // zero-fill padding row
      ushort4 z = {0, 0, 0, 0};
      *(ushort4*)(dst + lane * 4) = z;
      *(ushort4*)(dst + 256 + lane * 4) = z;
      return;
    }
    src = w + ((size_t)a * NC + c) * NK;
  }
  const float4 v0 = *(const float4*)(src + lane * 4);
  const float4 v1 = *(const float4*)(src + 256 + lane * 4);
  float ss = v0.x * v0.x + v0.y * v0.y + v0.z * v0.z + v0.w * v0.w +
             v1.x * v1.x + v1.y * v1.y + v1.z * v1.z + v1.w * v1.w;
  ss = waveReduceSum(ss);
  ss = __shfl(ss, 0);
  const float rn = 1.0f / fmaxf(sqrtf(ss), 1e-12f);
  ushort4 o0 = {f2bf(v0.x * rn), f2bf(v0.y * rn), f2bf(v0.z * rn), f2bf(v0.w * rn)};
  ushort4 o1 = {f2bf(v1.x * rn), f2bf(v1.y * rn), f2bf(v1.z * rn), f2bf(v1.w * rn)};
  *(ushort4*)(dst + lane * 4) = o0;
  *(ushort4*)(dst + 256 + lane * 4) = o1;
}

// cosine[b,c] = max_a dot(xn[b,:], wn[a,c,:])  via bf16 MFMA, fp32 accum.
// R8-proven skeleton (64x128 tile, 2 waves, double-buffer, ONE __syncthreads
// per step, slot-rotation swizzle, XCD swizzle, grid 768 = 3 blocks/CU),
// K-chunk widened to BK=64: 24 steps x 32 MFMA instead of 48 x 16.
// Rationale [R8/R11 counters]: step time ~1800cy >> work (~250cy) because
// each barrier drains that step's loads (vmcnt(0)); halving the number of
// drain points halves the serial latency chain. LDS 48KB keeps 3 blocks/CU.
// LDS slot layout: slot (kk*NG + g) = rows [g*16,g*16+16) x k-cols
// [kk*32,kk*32+32), each 512 ushorts; fragment read = slot base + rdoff.
__global__ __launch_bounds__(128) void cos_gemm_mfma(const ushort* __restrict__ Xb,
                                                     const ushort* __restrict__ Wb,
                                                     float* __restrict__ cosine) {
  __shared__ ushort sA0[64 * 64];   // 8 KB each (8 slots: kk*4+g)
  __shared__ ushort sA1[64 * 64];
  __shared__ ushort sB0[128 * 64];  // 16 KB each (16 slots: kk*8+g)
  __shared__ ushort sB1[128 * 64];
  const int tid = threadIdx.x;
  const int lane = tid & 63;
  const int w = tid >> 6;           // 0..1

  // swizzle: id = (cx&7) + 8*by + 128*(cx>>3)  (bijective on 8*16*6 = 768)
  const int id = blockIdx.x;
  const int cx = (id & 7) + ((id >> 7) << 3);   // 0..47
  const int by = (id >> 3) & 15;                // 0..15
  const int b0 = by * 64;
  const int c0 = cx * 128;

  // staging source: quad-contiguous rows, chunk rotated (R8-proven):
  const int lrow = lane >> 2;
  const int skg = ((lane & 3) - ((lane >> 3) & 3)) & 3;
  // wave w stages A row-groups {2w,2w+1}, B row-groups {4w..4w+3}, both kk
  const ushort* gA = Xb + (size_t)(b0 + w * 32 + lrow) * NK + skg * 8;
  const ushort* gB = Wb + (size_t)(c0 + w * 64 + lrow) * NK + skg * 8;
  const int w4 = w * 4;

  // fragment-read offset within a 16x32 slot: r*32 + (((kg+(r>>1))&3)*8)
  const int r = lane & 15;
  const int kg = lane >> 4;
  const int rdoff = r * 32 + (((kg + (r >> 1)) & 3) * 8);

  f32x4 best[4][4];
  f32x4 acc[4][4];
#pragma unroll
  for (int i = 0; i < 4; ++i)
#pragma unroll
    for (int j = 0; j < 4; ++j) {
#pragma unroll
      for (int q = 0; q < 4; ++q) best[i][j][q] = -INFINITY;
      acc[i][j] = (f32x4)(0.f);
    }

  // stage K-step tt (64 k-cols): 12 gload_lds per wave
#define STAGE(TT, SAw, SBw)                                                     \
  {                                                                             \
    const int tt_ = (TT);                                                       \
    const int kb = (tt_ & 7) << 6;                                              \
    const size_t boff = (size_t)(tt_ >> 3) * NCP * NK + kb;                     \
    _Pragma("unroll") for (int kk = 0; kk < 2; ++kk) {                          \
      _Pragma("unroll") for (int s = 0; s < 2; ++s)                             \
          load_lds16(gA + (size_t)s * 16 * NK + kb + kk * 32,                   \
                     (ushort*)SAw + (kk * 4 + 2 * w + s) * 512);                \
      _Pragma("unroll") for (int j = 0; j < 4; ++j)                             \
          load_lds16(gB + boff + (size_t)j * 16 * NK + kk * 32,                 \
                     (ushort*)SBw + (kk * 8 + w4 + j) * 512);                   \
    }                                                                           \
  }

  // prologue: stage t=0 into buffer 0
  STAGE(0, sA0, sB0)
  __syncthreads();

#define GEMM_BODY(T, SAr, SBr, SAw, SBw)                                        \
  {                                                                             \
    const int t_ = (T);                                                         \
    if (t_ + 1 < NT2) STAGE(t_ + 1, SAw, SBw)                                   \
    short8 af[4][2], bf[4][2];                                                  \
    _Pragma("unroll") for (int kk = 0; kk < 2; ++kk) {                          \
      _Pragma("unroll") for (int mi = 0; mi < 4; ++mi)                          \
          af[mi][kk] = *(const short8*)&SAr[(kk * 4 + mi) * 512 + rdoff];       \
      _Pragma("unroll") for (int ni = 0; ni < 4; ++ni)                          \
          bf[ni][kk] = *(const short8*)&SBr[(kk * 8 + w4 + ni) * 512 + rdoff];  \
    }                                                                           \
    _Pragma("unroll") for (int kk = 0; kk < 2; ++kk)                            \
        _Pragma("unroll") for (int mi = 0; mi < 4; ++mi)                        \
            _Pragma("unroll") for (int ni = 0; ni < 4; ++ni)                    \
                acc[mi][ni] = __builtin_amdgcn_mfma_f32_16x16x32_bf16(          \
                    af[mi][kk], bf[ni][kk], acc[mi][ni], 0, 0, 0);              \
    if ((t_ & 7) == 7) {                                                        \
      _Pragma("unroll") for (int i = 0; i < 4; ++i)                             \
          _Pragma("unroll") for (int j = 0; j < 4; ++j) {                       \
        _Pragma("unroll") for (int q = 0; q < 4; ++q)                           \
            best[i][j][q] = fmaxf(best[i][j][q], acc[i][j][q]);                 \
        acc[i][j] = (f32x4)(0.f);                                               \
      }                                                                         \
    }                                                                           \
    __syncthreads();                                                            \
  }

  for (int t = 0; t < NT2; t += 2) {
    GEMM_BODY(t, sA0, sB0, sA1, sB1)
    GEMM_BODY(t + 1, sA1, sB1, sA0, sB0)
  }
#undef GEMM_BODY
#undef STAGE

  // C/D layout: col = lane&15, row = (lane>>4)*4 + q   [measured m89/m91]
  const int q4 = (lane >> 4) * 4;
#pragma unroll
  for (int ni = 0; ni < 4; ++ni) {
    const int col = c0 + w * 64 + ni * 16 + r;
    if (col < NC) {
#pragma unroll
      for (int mi = 0; mi < 4; ++mi) {
        const int row0 = b0 + mi * 16 + q4;
#pragma unroll
        for (int q = 0; q < 4; ++q)
          cosine[(size_t)(row0 + q) * NC + col] = best[mi][ni][q];
      }
    }
  }
}

// Per-row loss (R5/R8-proven): 256 threads/row, register-resident 24/thread.
__global__ __launch_bounds__(256) void row_loss(const float* __restrict__ cosine,
                                                const int* __restrict__ label,
                                                float* __restrict__ loss_b,
                                                float* __restrict__ corr_b) {
  __shared__ float swv[4];
  __shared__ int swi[4];
  __shared__ float s_red[4];
  __shared__ float s_maxv;
  __shared__ float s_cosL;
  __shared__ float topv[6];
  __shared__ int topi[6];

  const int b = blockIdx.x, tid = threadIdx.x;
  const int wv = tid >> 6;
  const int lab = label[b];
  const float* row = cosine + (size_t)b * NC;

  float v[NPT];
  float bv = -INFINITY;
  int bi = -1;
#pragma unroll
  for (int j = 0; j < NPT; ++j) {
    const int i = tid + j * 256;
    v[j] = (i < NC) ? row[i] : -INFINITY;
    if (v[j] > bv) { bv = v[j]; bi = i; }
  }
  if (tid == (lab & 255)) s_cosL = v[lab >> 8];
  waveArgMax(bv, bi);
  if ((tid & 63) == 0) { swv[wv] = bv; swi[wv] = bi; }
  __syncthreads();
  if (tid == 0) {
    float mv = swv[0]; int mi = swi[0];
    for (int q = 1; q < 4; ++q)
      if (swv[q] > mv || (swv[q] == mv && (unsigned)swi[q] < (unsigned)mi)) { mv = swv[q]; mi = swi[q]; }
    s_maxv = mv; topv[0] = mv; topi[0] = mi;
  }
  __syncthreads();
  const float maxv = s_maxv;

  float ps = 0.f;
#pragma unroll
  for (int j = 0; j < NPT; ++j) ps += __expf(SCALE_F * (v[j] - maxv));
  ps = waveReduceSum(ps);
  if ((tid & 63) == 0) s_red[wv] = ps;

  unsigned excl = 0;
  {
    const int wi = topi[0];
    if ((wi & 255) == tid) excl |= 1u << (wi >> 8);
  }

  for (int e = 1; e < 6; ++e) {
    float lv = -INFINITY;
    int li = -1;
#pragma unroll
    for (int j = 0; j < NPT; ++j)
      if (!((excl >> j) & 1u) && v[j] > lv) { lv = v[j]; li = tid + j * 256; }
    waveArgMax(lv, li);
    if ((tid & 63) == 0) { swv[wv] = lv; swi[wv] = li; }
    __syncthreads();
    if (tid == 0) {
      float mv = swv[0]; int mi = swi[0];
      for (int q = 1; q < 4; ++q)
        if (swv[q] > mv || (swv[q] == mv && (unsigned)swi[q] < (unsigned)mi)) { mv = swv[q]; mi = swi[q]; }
      topv[e] = mv; topi[e] = mi;
    }
    __syncthreads();
    const int wi = topi[e];
    if ((wi & 255) == tid) excl |= 1u << (wi >> 8);
  }

  if (tid == 0) {
    const float S = s_red[0] + s_red[1] + s_red[2] + s_red[3];
    const float m = SCALE_F * maxv;
    const float cosL = s_cosL;
    const float sineL = sqrtf(fminf(fmaxf(1.f - cosL * cosL, 0.f), 1.f));
    const float phiL = (cosL - TH_F > 0.f) ? (cosL * COS_M_F - sineL * SIN_M_F) : (cosL - MM_F);
    float adj = __expf(SCALE_F * phiL - m) - __expf(SCALE_F * cosL - m);
    int cnt = 0;
    for (int e = 0; e < 6 && cnt < 5; ++e) {
      if (topi[e] == lab) continue;
      const float c = topv[e];
      const float sine = sqrtf(fminf(fmaxf(1.f - c * c, 0.f), 1.f));
      const float sp = (c - SUB_TH_F > 0.f) ? (c * SUB_COS_M_F - sine * SUB_SIN_M_F) : (c - SUB_MM_F);
      adj += __expf(SCALE_F * sp - m) - __expf(SCALE_F * c - m);
      ++cnt;
    }
    const float Sp = S + adj;
    loss_b[b] = (logf(Sp) + m) - SCALE_F * phiL;
    corr_b[b] = (topi[0] == lab) ? 1.f : 0.f;
  }
}

__global__ __launch_bounds__(256) void finalize(const float* __restrict__ loss_b,
                                                const float* __restrict__ corr_b,
                                                float* __restrict__ out) {
  const int tid = threadIdx.x;
  float ls = 0.f, cs = 0.f;
  for (int i = tid; i < NB; i += 256) { ls += loss_b[i]; cs += corr_b[i]; }
  ls = waveReduceSum(ls);
  cs = waveReduceSum(cs);
  __shared__ float sl[4], sc[4];
  if ((tid & 63) == 0) { sl[tid >> 6] = ls; sc[tid >> 6] = cs; }
  __syncthreads();
  if (tid == 0) {
    const float L = sl[0] + sl[1] + sl[2] + sl[3];
    const float Cr = sc[0] + sc[1] + sc[2] + sc[3];
    out[0] = L / (float)NB;
    out[1] = Cr / (float)NB * 100.f;
  }
}

extern "C" void kernel_launch(void* const* d_in, const int* in_sizes, int n_in,
                              void* d_out, int out_size, void* d_ws, size_t ws_size,
                              hipStream_t stream) {
  const float* x = (const float*)d_in[0];      // [1024, 512]
  const float* w = (const float*)d_in[1];      // [3, 5994, 512]
  const int* label = (const int*)d_in[2];      // [1024]
  float* out = (float*)d_out;                  // [2] = {loss, prec1}
  char* ws = (char*)d_ws;

  // workspace layout (bytes) — identical footprint to R5/R8 (proven):
  ushort* xb = (ushort*)ws;                                    // 1,048,576
  ushort* wb = (ushort*)(ws + 1048576);                        // 18,874,368
  float* cosine = (float*)(ws + 1048576 + 18874368);           // 24,551,424 (packed, stride 5994)
  float* loss_b = (float*)ws;                                  // reuses dead xb
  float* corr_b = (float*)(ws + 4096);

  norm_convert<<<(NB + NA * NCP) / 4, 256, 0, stream>>>(x, w, xb, wb);
  cos_gemm_mfma<<<16 * 48, 128, 0, stream>>>(xb, wb, cosine);
  row_loss<<<NB, 256, 0, stream>>>(cosine, label, loss_b, corr_b);
  finalize<<<1, 256, 0, stream>>>(loss_b, corr_b, out);
}

// Round 13
// 66.732 us; speedup vs baseline: 1.2438x; 1.1546x over previous
//
#include <hip/hip_runtime.h>
#include <math.h>

// Problem constants
#define NB 1024
#define NC 5994
#define NCP 6144   // padded row count for wb (48 c-tiles of 128)
#define NK 512
#define NA 3
#define NT 48      // total K-steps: NA * (NK/32)
#define SCALE_F 30.0f
#define NPT 24     // ceil(NC/256) for row_loss

// Margin constants
#define COS_M_F 0.9800665778412416f
#define SIN_M_F 0.19866933079506122f
#define TH_F (-0.9800665778412416f)
#define MM_F 0.039733866159012244f
#define SUB_COS_M_F 0.9982005399352042f
#define SUB_SIN_M_F (-0.05996400647944459f)
#define SUB_TH_F (-0.9982005399352042f)
#define SUB_MM_F 0.0035978403887666754f

typedef __attribute__((ext_vector_type(8))) short short8;   // 8 bf16 (4 VGPRs)
typedef __attribute__((ext_vector_type(4))) float f32x4;    // MFMA accumulator

__device__ __forceinline__ float waveReduceSum(float v) {
#pragma unroll
  for (int off = 32; off > 0; off >>= 1) v += __shfl_down(v, off);
  return v;
}

__device__ __forceinline__ void waveArgMax(float& v, int& i) {
#pragma unroll
  for (int off = 32; off > 0; off >>= 1) {
    float ov = __shfl_down(v, off);
    int oi = __shfl_down(i, off);
    if (ov > v || (ov == v && (unsigned)oi < (unsigned)i)) { v = ov; i = oi; }
  }
}

__device__ __forceinline__ ushort f2bf(float f) {
  unsigned u = __float_as_uint(f);
  u += 0x7FFFu + ((u >> 16) & 1u);
  return (ushort)(u >> 16);
}

__device__ __forceinline__ float bf2f(ushort u) {
  return __uint_as_float(((unsigned)u) << 16);
}

__device__ __forceinline__ void load_lds16(const ushort* g, ushort* l) {
  __builtin_amdgcn_global_load_lds(
      (const __attribute__((address_space(1))) unsigned int*)g,
      (__attribute__((address_space(3))) unsigned int*)l, 16, 0, 0);
}

// Fused L2-normalize + bf16 convert. 4 rows per 256-thread block (1 row/wave).
__global__ __launch_bounds__(256) void norm_convert(const float* __restrict__ x,
                                                    const float* __restrict__ w,
                                                    ushort* __restrict__ xb,
                                                    ushort* __restrict__ wb) {
  const int row = blockIdx.x * 4 + (threadIdx.x >> 6);
  const int lane = threadIdx.x & 63;
  const float* src;
  ushort* dst;
  if (row < NB) {
    src = x + (size_t)row * NK;
    dst = xb + (size_t)row * NK;
  } else {
    const int r = row - NB;           // 0 .. NA*NCP-1
    const int a = r / NCP, c = r % NCP;
    dst = wb + (size_t)r * NK;
    if (c >= NC) {                    // zero-fill padding row
      ushort4 z = {0, 0, 0, 0};
      *(ushort4*)(dst + lane * 4) = z;
      *(ushort4*)(dst + 256 + lane * 4) = z;
      return;
    }
    src = w + ((size_t)a * NC + c) * NK;
  }
  const float4 v0 = *(const float4*)(src + lane * 4);
  const float4 v1 = *(const float4*)(src + 256 + lane * 4);
  float ss = v0.x * v0.x + v0.y * v0.y + v0.z * v0.z + v0.w * v0.w +
             v1.x * v1.x + v1.y * v1.y + v1.z * v1.z + v1.w * v1.w;
  ss = waveReduceSum(ss);
  ss = __shfl(ss, 0);
  const float rn = 1.0f / fmaxf(sqrtf(ss), 1e-12f);
  ushort4 o0 = {f2bf(v0.x * rn), f2bf(v0.y * rn), f2bf(v0.z * rn), f2bf(v0.w * rn)};
  ushort4 o1 = {f2bf(v1.x * rn), f2bf(v1.y * rn), f2bf(v1.z * rn), f2bf(v1.w * rn)};
  *(ushort4*)(dst + lane * 4) = o0;
  *(ushort4*)(dst + 256 + lane * 4) = o1;
}

// cosine[b,c] = max_a dot(xn[b,:], wn[a,c,:])  via bf16 MFMA, fp32 accum.
// EXACT R8 kernel (proven fastest: 64x128 tile, 2 waves, double-buffer,
// ONE __syncthreads per K-step, slot-rotation swizzle = VMEM quad-coalesced
// + conflict-free ds_read, XCD swizzle, grid 768; 24KB LDS lets the
// scheduler backfill up to 6 blocks/CU — occupancy 14.8% vs 7.2% at 48KB,
// R12 lesson), with ONE change: epilogue stores bf16 (halves write traffic;
// loss mean-error ~2e-4, analyzed safe vs 0.306 threshold).
__global__ __launch_bounds__(128) void cos_gemm_mfma(const ushort* __restrict__ Xb,
                                                     const ushort* __restrict__ Wb,
                                                     ushort* __restrict__ cosb) {
  __shared__ ushort sA0[64 * 32];   // 4 KB each
  __shared__ ushort sA1[64 * 32];
  __shared__ ushort sB0[128 * 32];  // 8 KB each
  __shared__ ushort sB1[128 * 32];
  const int tid = threadIdx.x;
  const int lane = tid & 63;
  const int w = tid >> 6;           // 0..1

  // swizzle: id = (cx&7) + 8*by + 128*(cx>>3)  (bijective on 8*16*6 = 768)
  const int id = blockIdx.x;
  const int cx = (id & 7) + ((id >> 7) << 3);   // 0..47
  const int by = (id >> 3) & 15;                // 0..15
  const int b0 = by * 64;
  const int c0 = cx * 128;

  // staging source: quad-contiguous rows, chunk rotated (R8-proven):
  const int lrow = lane >> 2;
  const int skg = ((lane & 3) - ((lane >> 3) & 3)) & 3;
  const ushort* gA = Xb + (size_t)(b0 + w * 32 + lrow) * NK + skg * 8;
  const ushort* gB = Wb + (size_t)(c0 + w * 64 + lrow) * NK + skg * 8;
  const int ldsA = w * 1024;        // A sub-blocks {2w,2w+1}
  const int ldsB = w * 2048;        // B sub-blocks {4w..4w+3}
  const int w4 = w * 4;

  // fragment-read offset: r*32 + (((kg + (r>>1)) & 3) * 8)  (R8-proven)
  const int r = lane & 15;
  const int kg = lane >> 4;
  const int rdoff = r * 32 + (((kg + (r >> 1)) & 3) * 8);

  f32x4 best[4][4];
  f32x4 acc[4][4];
#pragma unroll
  for (int i = 0; i < 4; ++i)
#pragma unroll
    for (int j = 0; j < 4; ++j) {
#pragma unroll
      for (int q = 0; q < 4; ++q) best[i][j][q] = -INFINITY;
      acc[i][j] = (f32x4)(0.f);
    }

  // prologue: stage t=0 into buffer 0
  load_lds16(gA, (ushort*)sA0 + ldsA);
  load_lds16(gA + 16 * NK, (ushort*)sA0 + ldsA + 512);
#pragma unroll
  for (int j = 0; j < 4; ++j)
    load_lds16(gB + (size_t)j * 16 * NK, (ushort*)sB0 + ldsB + j * 512);
  __syncthreads();

#define GEMM_BODY(T, SAr, SBr, SAw, SBw)                                        \
  {                                                                             \
    const int t_ = (T);                                                         \
    if (t_ + 1 < NT) {                                                          \
      const int tn = t_ + 1;                                                    \
      const int k0 = (tn & 15) << 5;                                            \
      const size_t boff = (size_t)(tn >> 4) * NCP * NK + k0;                    \
      load_lds16(gA + k0, (ushort*)SAw + ldsA);                                 \
      load_lds16(gA + k0 + 16 * NK, (ushort*)SAw + ldsA + 512);                 \
      _Pragma("unroll") for (int j = 0; j < 4; ++j)                             \
          load_lds16(gB + boff + (size_t)j * 16 * NK,                           \
                     (ushort*)SBw + ldsB + j * 512);                            \
    }                                                                           \
    short8 af[4], bf[4];                                                        \
    _Pragma("unroll") for (int mi = 0; mi < 4; ++mi)                            \
        af[mi] = *(const short8*)&SAr[mi * 512 + rdoff];                        \
    _Pragma("unroll") for (int ni = 0; ni < 4; ++ni)                            \
        bf[ni] = *(const short8*)&SBr[(w4 + ni) * 512 + rdoff];                 \
    _Pragma("unroll") for (int mi = 0; mi < 4; ++mi)                            \
        _Pragma("unroll") for (int ni = 0; ni < 4; ++ni)                        \
            acc[mi][ni] = __builtin_amdgcn_mfma_f32_16x16x32_bf16(              \
                af[mi], bf[ni], acc[mi][ni], 0, 0, 0);                          \
    if ((t_ & 15) == 15) {                                                      \
      _Pragma("unroll") for (int i = 0; i < 4; ++i)                             \
          _Pragma("unroll") for (int j = 0; j < 4; ++j) {                       \
        _Pragma("unroll") for (int q = 0; q < 4; ++q)                           \
            best[i][j][q] = fmaxf(best[i][j][q], acc[i][j][q]);                 \
        acc[i][j] = (f32x4)(0.f);                                               \
      }                                                                         \
    }                                                                           \
    __syncthreads();                                                            \
  }

  for (int t = 0; t < NT; t += 2) {
    GEMM_BODY(t, sA0, sB0, sA1, sB1)
    GEMM_BODY(t + 1, sA1, sB1, sA0, sB0)
  }
#undef GEMM_BODY

  // C/D layout: col = lane&15, row = (lane>>4)*4 + q   [measured m89/m91]
  const int q4 = (lane >> 4) * 4;
#pragma unroll
  for (int ni = 0; ni < 4; ++ni) {
    const int col = c0 + w * 64 + ni * 16 + r;
    if (col < NC) {
#pragma unroll
      for (int mi = 0; mi < 4; ++mi) {
        const int row0 = b0 + mi * 16 + q4;
#pragma unroll
        for (int q = 0; q < 4; ++q)
          cosb[(size_t)(row0 + q) * NC + col] = f2bf(best[mi][ni][q]);
      }
    }
  }
}

// Per-row loss (R8-proven structure): 256 threads/row, register-resident
// 24 elems/thread; input is now bf16 (half the read bytes).
__global__ __launch_bounds__(256) void row_loss(const ushort* __restrict__ cosb,
                                                const int* __restrict__ label,
                                                float* __restrict__ loss_b,
                                                float* __restrict__ corr_b) {
  __shared__ float swv[4];
  __shared__ int swi[4];
  __shared__ float s_red[4];
  __shared__ float s_maxv;
  __shared__ float s_cosL;
  __shared__ float topv[6];
  __shared__ int topi[6];

  const int b = blockIdx.x, tid = threadIdx.x;
  const int wv = tid >> 6;
  const int lab = label[b];
  const ushort* row = cosb + (size_t)b * NC;

  float v[NPT];
  float bv = -INFINITY;
  int bi = -1;
#pragma unroll
  for (int j = 0; j < NPT; ++j) {
    const int i = tid + j * 256;
    v[j] = (i < NC) ? bf2f(row[i]) : -INFINITY;
    if (v[j] > bv) { bv = v[j]; bi = i; }
  }
  if (tid == (lab & 255)) s_cosL = v[lab >> 8];
  waveArgMax(bv, bi);
  if ((tid & 63) == 0) { swv[wv] = bv; swi[wv] = bi; }
  __syncthreads();
  if (tid == 0) {
    float mv = swv[0]; int mi = swi[0];
    for (int q = 1; q < 4; ++q)
      if (swv[q] > mv || (swv[q] == mv && (unsigned)swi[q] < (unsigned)mi)) { mv = swv[q]; mi = swi[q]; }
    s_maxv = mv; topv[0] = mv; topi[0] = mi;
  }
  __syncthreads();
  const float maxv = s_maxv;

  float ps = 0.f;
#pragma unroll
  for (int j = 0; j < NPT; ++j) ps += __expf(SCALE_F * (v[j] - maxv));
  ps = waveReduceSum(ps);
  if ((tid & 63) == 0) s_red[wv] = ps;

  unsigned excl = 0;
  {
    const int wi = topi[0];
    if ((wi & 255) == tid) excl |= 1u << (wi >> 8);
  }

  for (int e = 1; e < 6; ++e) {
    float lv = -INFINITY;
    int li = -1;
#pragma unroll
    for (int j = 0; j < NPT; ++j)
      if (!((excl >> j) & 1u) && v[j] > lv) { lv = v[j]; li = tid + j * 256; }
    waveArgMax(lv, li);
    if ((tid & 63) == 0) { swv[wv] = lv; swi[wv] = li; }
    __syncthreads();
    if (tid == 0) {
      float mv = swv[0]; int mi = swi[0];
      for (int q = 1; q < 4; ++q)
        if (swv[q] > mv || (swv[q] == mv && (unsigned)swi[q] < (unsigned)mi)) { mv = swv[q]; mi = swi[q]; }
      topv[e] = mv; topi[e] = mi;
    }
    __syncthreads();
    const int wi = topi[e];
    if ((wi & 255) == tid) excl |= 1u << (wi >> 8);
  }

  if (tid == 0) {
    const float S = s_red[0] + s_red[1] + s_red[2] + s_red[3];
    const float m = SCALE_F * maxv;
    const float cosL = s_cosL;
    const float sineL = sqrtf(fminf(fmaxf(1.f - cosL * cosL, 0.f), 1.f));
    const float phiL = (cosL - TH_F > 0.f) ? (cosL * COS_M_F - sineL * SIN_M_F) : (cosL - MM_F);
    float adj = __expf(SCALE_F * phiL - m) - __expf(SCALE_F * cosL - m);
    int cnt = 0;
    for (int e = 0; e < 6 && cnt < 5; ++e) {
      if (topi[e] == lab) continue;
      const float c = topv[e];
      const float sine = sqrtf(fminf(fmaxf(1.f - c * c, 0.f), 1.f));
      const float sp = (c - SUB_TH_F > 0.f) ? (c * SUB_COS_M_F - sine * SUB_SIN_M_F) : (c - SUB_MM_F);
      adj += __expf(SCALE_F * sp - m) - __expf(SCALE_F * c - m);
      ++cnt;
    }
    const float Sp = S + adj;
    loss_b[b] = (logf(Sp) + m) - SCALE_F * phiL;
    corr_b[b] = (topi[0] == lab) ? 1.f : 0.f;
  }
}

__global__ __launch_bounds__(256) void finalize(const float* __restrict__ loss_b,
                                                const float* __restrict__ corr_b,
                                                float* __restrict__ out) {
  const int tid = threadIdx.x;
  float ls = 0.f, cs = 0.f;
  for (int i = tid; i < NB; i += 256) { ls += loss_b[i]; cs += corr_b[i]; }
  ls = waveReduceSum(ls);
  cs = waveReduceSum(cs);
  __shared__ float sl[4], sc[4];
  if ((tid & 63) == 0) { sl[tid >> 6] = ls; sc[tid >> 6] = cs; }
  __syncthreads();
  if (tid == 0) {
    const float L = sl[0] + sl[1] + sl[2] + sl[3];
    const float Cr = sc[0] + sc[1] + sc[2] + sc[3];
    out[0] = L / (float)NB;
    out[1] = Cr / (float)NB * 100.f;
  }
}

extern "C" void kernel_launch(void* const* d_in, const int* in_sizes, int n_in,
                              void* d_out, int out_size, void* d_ws, size_t ws_size,
                              hipStream_t stream) {
  const float* x = (const float*)d_in[0];      // [1024, 512]
  const float* w = (const float*)d_in[1];      // [3, 5994, 512]
  const int* label = (const int*)d_in[2];      // [1024]
  float* out = (float*)d_out;                  // [2] = {loss, prec1}
  char* ws = (char*)d_ws;

  // workspace layout (bytes) — within the R5/R8-proven footprint:
  ushort* xb = (ushort*)ws;                                    // 1,048,576
  ushort* wb = (ushort*)(ws + 1048576);                        // 18,874,368
  ushort* cosb = (ushort*)(ws + 1048576 + 18874368);           // 12,275,712 (bf16, stride 5994)
  float* loss_b = (float*)ws;                                  // reuses dead xb
  float* corr_b = (float*)(ws + 4096);

  norm_convert<<<(NB + NA * NCP) / 4, 256, 0, stream>>>(x, w, xb, wb);
  cos_gemm_mfma<<<16 * 48, 128, 0, stream>>>(xb, wb, cosb);
  row_loss<<<NB, 256, 0, stream>>>(cosb, label, loss_b, corr_b);
  finalize<<<1, 256, 0, stream>>>(loss_b, corr_b, out);
}